// Round 1
// baseline (140.406 us; speedup 1.0000x reference)
//
#include <hip/hip_runtime.h>

typedef unsigned short u16;
typedef unsigned int u32;
typedef __attribute__((ext_vector_type(8))) short short8;
typedef __attribute__((ext_vector_type(8))) __bf16 bf16x8;
typedef __attribute__((ext_vector_type(4))) float f32x4;
typedef __attribute__((ext_vector_type(16))) float f32x16;
typedef __attribute__((ext_vector_type(4))) unsigned short us4;
typedef __attribute__((ext_vector_type(4))) unsigned int u32x4;

#define DEVFN static __device__ __forceinline__

DEVFN u16 f2bf(float f) {
  u32 u = __float_as_uint(f);
  return (u16)((u + 0x7fffu + ((u >> 16) & 1u)) >> 16);  // RNE, finite inputs
}

#if __has_builtin(__builtin_amdgcn_exp2f)
DEVFN float fexp2(float x) { return __builtin_amdgcn_exp2f(x); }
#else
DEVFN float fexp2(float x) { return exp2f(x); }
#endif

// ---- MFMA wrappers: tolerant of short8-typed or bf16x8-typed builtins ----
template <typename T>
DEVFN auto mfma16_imp(T a, T b, f32x4 c, int)
    -> decltype(__builtin_amdgcn_mfma_f32_16x16x32_bf16(a, b, c, 0, 0, 0)) {
  return __builtin_amdgcn_mfma_f32_16x16x32_bf16(a, b, c, 0, 0, 0);
}
template <typename T>
DEVFN f32x4 mfma16_imp(T a, T b, f32x4 c, long) {
  return __builtin_amdgcn_mfma_f32_16x16x32_bf16(
      __builtin_bit_cast(bf16x8, a), __builtin_bit_cast(bf16x8, b), c, 0, 0, 0);
}
DEVFN f32x4 MFMA(short8 a, short8 b, f32x4 c) { return mfma16_imp(a, b, c, 0); }

template <typename T>
DEVFN auto mfma32_imp(T a, T b, f32x16 c, int)
    -> decltype(__builtin_amdgcn_mfma_f32_32x32x16_bf16(a, b, c, 0, 0, 0)) {
  return __builtin_amdgcn_mfma_f32_32x32x16_bf16(a, b, c, 0, 0, 0);
}
template <typename T>
DEVFN f32x16 mfma32_imp(T a, T b, f32x16 c, long) {
  return __builtin_amdgcn_mfma_f32_32x32x16_bf16(
      __builtin_bit_cast(bf16x8, a), __builtin_bit_cast(bf16x8, b), c, 0, 0, 0);
}
DEVFN f32x16 MFMA32(short8 a, short8 b, f32x16 c) { return mfma32_imp(a, b, c, 0); }

// ---- async global->LDS: dest = uniform base + lane*16 ----
DEVFN void gload_lds16(const u16* g, u16* l) {
  __builtin_amdgcn_global_load_lds(
      (__attribute__((address_space(1))) void*)g,
      (__attribute__((address_space(3))) void*)l, 16, 0, 0);
}

DEVFN u32 cvtpk_bf16(float lo, float hi) {
  u32 w;
  asm("v_cvt_pk_bf16_f32 %0, %1, %2" : "=v"(w) : "v"(lo), "v"(hi));
  return w;
}

// V scatter-transpose into V^T LDS tile with bank-spread swizzle.
// Layout must match PV read: Vs[d*64 + ((kvhi ^ (d&7) ^ ((d>>3)&7))*8) + kvlo]
DEVFN void vscatter(int tid, short8 a, short8 b, u16* dst) {
#pragma unroll
  for (int c = 0; c < 2; ++c) {
    short8 vv = c ? b : a;
    int gg = c * 256 + tid;
    int kv = gg >> 3, d0 = (gg & 7) * 8;
    int kvhi = kv >> 3, kvlo = kv & 7;
#pragma unroll
    for (int i = 0; i < 8; ++i) {
      int d = d0 + i;
      dst[d * 64 + ((kvhi ^ (d & 7) ^ ((d >> 3) & 7)) * 8) + kvlo] = (u16)vv[i];
    }
  }
}

// ================= f32 -> bf16 conversion =================
__global__ void __launch_bounds__(256) cvt_kernel(const float* __restrict__ in,
                                                  u16* __restrict__ out, int n4) {
  int i = blockIdx.x * 256 + threadIdx.x;
  if (i < n4) {
    f32x4 v = ((const f32x4*)in)[i];
    us4 o;
    o[0] = f2bf(v[0]); o[1] = f2bf(v[1]); o[2] = f2bf(v[2]); o[3] = f2bf(v[3]);
    ((us4*)out)[i] = o;
  }
}

// ================= GEMM: C[M,N] = A[M,K] @ B[N,K]^T (bf16 in, fp32 acc) ===
template <int F32OUT>
__global__ void __launch_bounds__(256) gemm_bt(
    const u16* __restrict__ A, const u16* __restrict__ Bm,
    u16* __restrict__ Cbf, float* __restrict__ Cf, const float* __restrict__ bias,
    int M, int N, int K) {
  __shared__ u16 As[128 * 32];
  __shared__ u16 Bs[128 * 32];
  const int tid = threadIdx.x;
  const int wave = tid >> 6, lane = tid & 63;
  const int bm = blockIdx.x * 128, bn = blockIdx.y * 128;
  const int wr = (wave >> 1) * 64, wc = (wave & 1) * 64;
  const int srow = lane >> 2, scol = (lane & 3) * 8;
  const int fr = lane & 15, fk = (lane >> 4) * 8;

  f32x4 acc[4][4] = {};

  for (int k0 = 0; k0 < K; k0 += 32) {
    __syncthreads();
#pragma unroll
    for (int t = 0; t < 2; ++t) {
      int rr = (wave * 2 + t) * 16 + srow;
      gload_lds16(A + (size_t)(bm + rr) * K + k0 + scol, As + (wave * 2 + t) * 512);
      gload_lds16(Bm + (size_t)(bn + rr) * K + k0 + scol, Bs + (wave * 2 + t) * 512);
    }
    __syncthreads();
    short8 af[4], bf[4];
#pragma unroll
    for (int i = 0; i < 4; ++i) {
      af[i] = *(const short8*)(As + (wr + i * 16 + fr) * 32 + fk);
      bf[i] = *(const short8*)(Bs + (wc + i * 16 + fr) * 32 + fk);
    }
#pragma unroll
    for (int mi = 0; mi < 4; ++mi)
#pragma unroll
      for (int ni = 0; ni < 4; ++ni)
        acc[mi][ni] = MFMA(af[mi], bf[ni], acc[mi][ni]);
  }

  const int orow = (lane >> 4) * 4, ocol = lane & 15;
#pragma unroll
  for (int mi = 0; mi < 4; ++mi)
#pragma unroll
    for (int ni = 0; ni < 4; ++ni)
#pragma unroll
      for (int r = 0; r < 4; ++r) {
        size_t row = (size_t)(bm + wr + mi * 16 + orow + r);
        size_t col = (size_t)(bn + wc + ni * 16 + ocol);
        if (F32OUT)
          Cf[row * N + col] = acc[mi][ni][r] + bias[col];
        else
          Cbf[row * N + col] = f2bf(acc[mi][ni][r]);
      }
}

// ================= Flash attention v2: swapped-operand 32x32 =================
// qkv: [4096, 3072] bf16. Grid (16 qblk, 16 heads, 2 batch), 256 thr (4 waves).
// Wave owns 32 q-rows (lane&31 = q); KVBLK=64; S^T = K.Q^T so softmax state is
// per-lane scalar; O^T = V^T.P^T; P redistributed in-register (cvt_pk+permlane).
// v2: double-buffered K/V staging, single barrier/tile, async-issue at top,
// V scatter after PV (load latency hidden under QK+softmax+PV compute).
__global__ void __launch_bounds__(256) attn_kernel(const u16* __restrict__ qkv,
                                                   u16* __restrict__ attn_out) {
  __shared__ u16 Ks[2][64 * 64];  // K[kv][d], chunk ^= (kv&7)
  __shared__ u16 Vs[2][64 * 64];  // V^T[d][kv], chunk ^= (d&7)^((d>>3)&7)

  const int tid = threadIdx.x;
  const int wave = tid >> 6, lane = tid & 63;
  const int q5 = lane & 31, hi = lane >> 5;
  const int qb = blockIdx.x, h = blockIdx.y, b = blockIdx.z;
  const size_t tok0 = (size_t)b * 2048;
  const float SCALE = 0.18033688011112042f;  // 0.125 * log2(e)

  // Q B-frags: lane q5 holds Q[q][ks*16 + hi*8 + j]
  const size_t qrow = tok0 + qb * 128 + wave * 32 + q5;
  const u16* qp = qkv + qrow * 3072 + h * 64 + hi * 8;
  short8 qf[4];
#pragma unroll
  for (int ks = 0; ks < 4; ++ks) qf[ks] = *(const short8*)(qp + ks * 16);

  const u16* kbase = qkv + tok0 * 3072 + 1024 + h * 64;
  const u16* vbase = qkv + tok0 * 3072 + 2048 + h * 64;

  // K staging src (per lane, static): row_in_8 = lane>>3, src chunk = (lane&7)^(lane>>3)
  const int k_srcoff = (((lane & 7) ^ (lane >> 3)) * 8);
  const int k_rowl = lane >> 3;
  // V load indices (per thread, static)
  const int v_kv0 = tid >> 3, v_d0 = (tid & 7) * 8;          // c=0
  const int v_kv1 = (256 + tid) >> 3;                        // c=1 (same d0)

  float m_run = -1e30f, l_run = 0.f;
  f32x16 o0 = {}, o1 = {};

  // ---- prologue: stage tile 0 into buffer 0 ----
#pragma unroll
  for (int c = 0; c < 2; ++c) {
    int row = (c * 4 + wave) * 8 + k_rowl;
    gload_lds16(kbase + (size_t)row * 3072 + k_srcoff, Ks[0] + (c * 4 + wave) * 512);
  }
  {
    short8 va = *(const short8*)(vbase + (size_t)v_kv0 * 3072 + v_d0);
    short8 vb = *(const short8*)(vbase + (size_t)v_kv1 * 3072 + v_d0);
    vscatter(tid, va, vb, Vs[0]);
  }
  __syncthreads();  // drains vmcnt (K gload_lds) + lgkm (V scatter)

  for (int t = 0; t < 32; ++t) {
    const int cur = t & 1, nxt = cur ^ 1;
    const int kv1 = (t + 1) << 6;
    short8 vna = {}, vnb = {};
    if (t < 31) {
      // ---- async-issue next tile: K direct-to-LDS, V to regs ----
#pragma unroll
      for (int c = 0; c < 2; ++c) {
        int row = (c * 4 + wave) * 8 + k_rowl;
        gload_lds16(kbase + (size_t)(kv1 + row) * 3072 + k_srcoff,
                    Ks[nxt] + (c * 4 + wave) * 512);
      }
      vna = *(const short8*)(vbase + (size_t)(kv1 + v_kv0) * 3072 + v_d0);
      vnb = *(const short8*)(vbase + (size_t)(kv1 + v_kv1) * 3072 + v_d0);
    }

    // ---- S^T = K . Q^T : 2 tiles (kv 0-31 / 32-63), 4 k-steps ----
    const u16* Kc = Ks[cur];
    f32x16 s0 = {}, s1 = {};
#pragma unroll
    for (int ks = 0; ks < 4; ++ks) {
      int ch = ((ks * 2 + hi) ^ (q5 & 7)) * 8;
      short8 k0 = *(const short8*)(Kc + q5 * 64 + ch);
      short8 k1 = *(const short8*)(Kc + (32 + q5) * 64 + ch);
      s0 = MFMA32(k0, qf[ks], s0);
      s1 = MFMA32(k1, qf[ks], s1);
    }

    // ---- online softmax, per-lane scalars (lane owns q = q5) ----
    // tree-max (dep depth ~5 instead of 32; compiler can fuse to v_max3)
    float mt[8];
#pragma unroll
    for (int i = 0; i < 8; ++i)
      mt[i] = fmaxf(fmaxf(s0[i], s0[i + 8]), fmaxf(s1[i], s1[i + 8]));
    float pmax = fmaxf(fmaxf(fmaxf(mt[0], mt[1]), fmaxf(mt[2], mt[3])),
                       fmaxf(fmaxf(mt[4], mt[5]), fmaxf(mt[6], mt[7])));
    pmax = fmaxf(pmax, __shfl_xor(pmax, 32, 64));
    float mraw = pmax * SCALE;

    if (__any(mraw > m_run + 8.f)) {  // T13 defer-max, wave-uniform
      float mn = fmaxf(m_run, mraw);
      float alpha = fexp2(m_run - mn);
#pragma unroll
      for (int i = 0; i < 16; ++i) { o0[i] *= alpha; o1[i] *= alpha; }
      l_run *= alpha;
      m_run = mn;
    }

    float p0[16], p1[16];
    float rs = 0.f;
#pragma unroll
    for (int i = 0; i < 16; ++i) {
      p0[i] = fexp2(fmaf(s0[i], SCALE, -m_run));
      p1[i] = fexp2(fmaf(s1[i], SCALE, -m_run));
      rs += p0[i] + p1[i];
    }
    rs += __shfl_xor(rs, 32, 64);
    l_run += rs;

    // ---- P^T -> PV B-frags in-register (cvt_pk + permlane32_swap) ----
    u32 w0[4][2], w1[4][2];
#pragma unroll
    for (int a = 0; a < 4; ++a) {
      w0[a][0] = cvtpk_bf16(p0[4 * a], p0[4 * a + 1]);
      w0[a][1] = cvtpk_bf16(p0[4 * a + 2], p0[4 * a + 3]);
      w1[a][0] = cvtpk_bf16(p1[4 * a], p1[4 * a + 1]);
      w1[a][1] = cvtpk_bf16(p1[4 * a + 2], p1[4 * a + 3]);
    }
    short8 pb[4];
#pragma unroll
    for (int ks = 0; ks < 4; ++ks) {
      int e = ks & 1;
      u32 x0 = (ks < 2) ? w0[2 * e][0] : w1[2 * e][0];
      u32 y0 = (ks < 2) ? w0[2 * e + 1][0] : w1[2 * e + 1][0];
      u32 x1 = (ks < 2) ? w0[2 * e][1] : w1[2 * e][1];
      u32 y1 = (ks < 2) ? w0[2 * e + 1][1] : w1[2 * e + 1][1];
      asm("v_permlane32_swap_b32 %0, %1" : "+v"(x0), "+v"(y0));
      asm("v_permlane32_swap_b32 %0, %1" : "+v"(x1), "+v"(y1));
      u32x4 tt = {x0, x1, y0, y1};  // words j={0,1},{2,3},{4,5},{6,7}
      pb[ks] = __builtin_bit_cast(short8, tt);
    }

    // ---- O^T += V^T . P^T ----
    const u16* Vc = Vs[cur];
#pragma unroll
    for (int ks = 0; ks < 4; ++ks) {
      int ch0 = ((ks * 2 + hi) ^ (q5 & 7) ^ ((q5 >> 3) & 7)) * 8;
      int ch1 = ch0 ^ (4 * 8);  // row 32+q5: (d>>3) flips bit 2
      short8 v0 = *(const short8*)(Vc + q5 * 64 + ch0);
      short8 v1 = *(const short8*)(Vc + (32 + q5) * 64 + ch1);
      o0 = MFMA32(v0, pb[ks], o0);
      o1 = MFMA32(v1, pb[ks], o1);
    }

    // ---- late V scatter into next buffer (vmcnt wait lands here) ----
    if (t < 31) vscatter(tid, vna, vnb, Vs[nxt]);

    __syncthreads();  // one barrier per tile: publishes Ks/Vs[nxt]
  }

  // ---- epilogue: O^T[d][q], lane q5; d = (reg&3)+8*(reg>>2)+4*hi+32*dt ----
  float inv = 1.f / l_run;
#pragma unroll
  for (int dt = 0; dt < 2; ++dt)
#pragma unroll
    for (int g = 0; g < 4; ++g) {
      us4 st;
#pragma unroll
      for (int c2 = 0; c2 < 4; ++c2) {
        float val = (dt == 0 ? o0[4 * g + c2] : o1[4 * g + c2]) * inv;
        st[c2] = f2bf(val);
      }
      int col = h * 64 + dt * 32 + 8 * g + 4 * hi;
      *(us4*)(attn_out + qrow * 1024 + col) = st;
    }
}

// ================= launcher =================
extern "C" void kernel_launch(void* const* d_in, const int* in_sizes, int n_in,
                              void* d_out, int out_size, void* d_ws, size_t ws_size,
                              hipStream_t stream) {
  const float* x = (const float*)d_in[0];
  const float* Wqkv = (const float*)d_in[1];
  const float* Wproj = (const float*)d_in[2];
  const float* bproj = (const float*)d_in[3];
  float* out = (float*)d_out;

  char* ws = (char*)d_ws;
  u16* x_bf     = (u16*)(ws);                 //  8 MB  [4096,1024]
  u16* wqkv_bf  = (u16*)(ws + 8388608);       //  6 MB  [3072,1024]
  u16* wproj_bf = (u16*)(ws + 14680064);      //  2 MB  [1024,1024]
  u16* qkv_bf   = (u16*)(ws + 16777216);      // 24 MB  [4096,3072]
  u16* attn_bf  = (u16*)(ws + 41943040);      //  8 MB  [4096,1024]

  cvt_kernel<<<4096, 256, 0, stream>>>(x, x_bf, 1048576);
  cvt_kernel<<<3072, 256, 0, stream>>>(Wqkv, wqkv_bf, 786432);
  cvt_kernel<<<1024, 256, 0, stream>>>(Wproj, wproj_bf, 262144);

  dim3 g1(32, 24);
  gemm_bt<0><<<g1, 256, 0, stream>>>(x_bf, wqkv_bf, qkv_bf, nullptr, nullptr,
                                     4096, 3072, 1024);

  dim3 g2(16, 16, 2);
  attn_kernel<<<g2, 256, 0, stream>>>(qkv_bf, attn_bf);

  dim3 g3(32, 8);
  gemm_bt<1><<<g3, 256, 0, stream>>>(attn_bf, wproj_bf, nullptr, out, bproj,
                                     4096, 1024, 1024);
}